// Round 4
// baseline (464.320 us; speedup 1.0000x reference)
//
#include <hip/hip_runtime.h>
#include <stdint.h>

#define SEQ 4096
#define DIM 1024

typedef __bf16 bf16x8 __attribute__((ext_vector_type(8)));
typedef float f32x4 __attribute__((ext_vector_type(4)));
typedef unsigned short u16;

__device__ __forceinline__ u16 f2bf(float f) {
    unsigned u = __float_as_uint(f);
    u += 0x7fffu + ((u >> 16) & 1u);     // RNE
    return (u16)(u >> 16);
}
__device__ __forceinline__ float bf2f(u16 h) {
    return __uint_as_float(((unsigned)h) << 16);
}

// global(16B) -> LDS direct copy; LDS dest is wave-uniform base + lane*16.
__device__ __forceinline__ void gload16(const u16* g, u16* l) {
    __builtin_amdgcn_global_load_lds(
        (const __attribute__((address_space(1))) void*)g,
        (__attribute__((address_space(3))) void*)l, 16, 0, 0);
}

// ---------------------------------------------------------------------------
// Kernel 1: h = rmsnorm(emb[x]) * norm_w, written as COMBINED hi|lo bf16
// hhl[4096][2048]: cols 0-1023 = hi, 1024-2047 = lo.
// ---------------------------------------------------------------------------
__global__ __launch_bounds__(256) void embed_rmsnorm_split(
    const int* __restrict__ x, const float* __restrict__ emb,
    const float* __restrict__ nw, u16* __restrict__ hhl)
{
    const int row  = blockIdx.x;
    const int t    = threadIdx.x;
    const int lane = t & 63, wave = t >> 6;

    bool i64 = true;
    #pragma unroll
    for (int i = 1; i < 128; i += 2) i64 = i64 && (x[i] == 0);
    const int id = i64 ? x[2 * row] : x[row];

    float4 e = *(const float4*)(emb + (size_t)id * DIM + t * 4);
    float ss = e.x*e.x + e.y*e.y + e.z*e.z + e.w*e.w;
    #pragma unroll
    for (int off = 32; off > 0; off >>= 1) ss += __shfl_down(ss, off);

    __shared__ float red[4];
    if (lane == 0) red[wave] = ss;
    __syncthreads();
    float sum = red[0] + red[1] + red[2] + red[3];
    float scale = rsqrtf(sum * (1.0f / DIM) + 1.1920929e-7f);  // fp32 eps

    float4 n = *(const float4*)(nw + t * 4);
    float o0 = e.x * scale * n.x;
    float o1 = e.y * scale * n.y;
    float o2 = e.z * scale * n.z;
    float o3 = e.w * scale * n.w;
    ushort4 oh, ol;
    u16 b;
    b = f2bf(o0); oh.x = b; ol.x = f2bf(o0 - bf2f(b));
    b = f2bf(o1); oh.y = b; ol.y = f2bf(o1 - bf2f(b));
    b = f2bf(o2); oh.z = b; ol.z = f2bf(o2 - bf2f(b));
    b = f2bf(o3); oh.w = b; ol.w = f2bf(o3 - bf2f(b));
    *(ushort4*)(hhl + (size_t)row * 2048 + t * 4)        = oh;
    *(ushort4*)(hhl + (size_t)row * 2048 + t * 4 + 1024) = ol;
}

// ---------------------------------------------------------------------------
// Kernel 1b: split Wq/Wk/Wv fp32 -> COMBINED hi|lo bf16 Whl[3072][2048]
// (rows 0-1023 = Wq, 1024-2047 = Wk, 2048-3071 = Wv; cols hi|lo)
// ---------------------------------------------------------------------------
__global__ __launch_bounds__(256) void split_w(
    const float* __restrict__ W0, const float* __restrict__ W1,
    const float* __restrict__ W2, u16* __restrict__ Whl)
{
    const float* W = (blockIdx.y == 0) ? W0 : (blockIdx.y == 1) ? W1 : W2;
    const int i   = (blockIdx.x * 256 + threadIdx.x) * 4;
    const int row = i >> 10;
    const int col = i & 1023;
    float4 w = *(const float4*)(W + i);
    ushort4 h, l;
    u16 b;
    b = f2bf(w.x); h.x = b; l.x = f2bf(w.x - bf2f(b));
    b = f2bf(w.y); h.y = b; l.y = f2bf(w.y - bf2f(b));
    b = f2bf(w.z); h.z = b; l.z = f2bf(w.z - bf2f(b));
    b = f2bf(w.w); h.w = b; l.w = f2bf(w.w - bf2f(b));
    u16* d = Whl + (size_t)(blockIdx.y * 1024 + row) * 2048 + col;
    *(ushort4*)(d)        = h;
    *(ushort4*)(d + 1024) = l;
}

// ---------------------------------------------------------------------------
// Kernel 2: shared 256x256 8-phase virtual-K'=3072 GEMM (T2 fixed-swizzle +
// T3/T4 counted vmcnt + T5 setprio). 8 waves (2Mx4N), BK=64, 128 KiB LDS
// double-buffer, 48 K-tiles.
//
// Segment maps (identical for both uses):
//   A' cols: ka = k'<2048 ? k' : k'-2048   -> [Ahi | Alo | Ahi]
//   B' cols: kb = k'<1024 ? k' : k'-1024   -> [Bhi | Bhi | Blo]
//   sum = Ah.Bh + Al.Bh + Ah.Bl  (split-precision product)
// EPI=0: Sc = q.k^T  (A=qhl, B=khl, fp32 C [SEQ,SEQ])
// EPI=1: QKV         (A=hhl, B=Whl, split-write qhl/khl + vT transposed)
//
// Swizzle (both-sides involution, bank-derived):
//   LDS[r][c] = global[r][c ^ 8*(r&7)]  (u16 units; rows are 128 B = 32 dwords
//   == 0 mod 32 banks, so all 3 low row bits must rotate the col bank-quads).
//   write side: source col = 8*((t&7) ^ ((t>>3)&7));  read side:
//   col(ks) = 8*((half+4*ks) ^ (l16&7)) -> each 16-lane group covers all 8
//   bank-quads 2-way (free, m136).
// ---------------------------------------------------------------------------
#define SC_NT 48
template<int EPI>
__global__ __launch_bounds__(512, 2) void gemm3072_8ph(
    const u16* __restrict__ A, const u16* __restrict__ B,
    float* __restrict__ C,
    u16* __restrict__ O0, u16* __restrict__ O1, u16* __restrict__ OT)
{
    __shared__ __align__(16) u16 Alds[2][256 * 64];
    __shared__ __align__(16) u16 Blds[2][256 * 64];

    const int tid  = threadIdx.x;
    const int lane = tid & 63;
    const int wid  = tid >> 6;
    const int wm   = wid >> 2;      // 0..1
    const int wn   = wid & 3;       // 0..3
    const int l16  = lane & 15;
    const int half = lane >> 4;     // 0..3

    // XCD-aware bijective swizzle (nwg = 256 or 192, both % 8 == 0)
    const int nx  = gridDim.x;
    const int nwg = nx * gridDim.y;
    const int wg  = blockIdx.y * nx + blockIdx.x;
    const int swz = (wg & 7) * (nwg >> 3) + (wg >> 3);
    const int m0  = (swz / nx) * 256;
    const int n0  = (swz % nx) * 256;

    // staging addresses (pre-swizzled global source, linear LDS dest)
    const int srow = tid >> 3;                              // 0..63 within unit
    const int scol = (((tid & 7) ^ ((tid >> 3) & 7))) * 8;  // inverse swizzle
    const u16* paq[4];
    const u16* pbq[4];
    #pragma unroll
    for (int q = 0; q < 4; ++q) {
        paq[q] = A + (size_t)(m0 + q * 64 + srow) * 2048 + scol;
        pbq[q] = B + (size_t)(n0 + q * 64 + srow) * 2048 + scol;
    }

    // ds_read col offsets (swizzled): col(ks) = 8*((half+4ks) ^ (l16&7))
    const int s   = l16 & 7;
    const int c0  = (half ^ s) * 8;     // ks=0
    const int c1  = c0 ^ 32;            // ks=1  ((half+4)^s)*8
    const int ar  = (wm * 128 + l16) * 64;   // A row base (+i*1024, +4096 quad1)
    const int br  = (wn * 64  + l16) * 64;   // B row base (+g*1024, +2048 pair1)

    // -------- prologue: stage tile0 -> buf0, tile1 -> buf1
    {
        u16* a0d = &Alds[0][wid * 512];
        u16* b0d = &Blds[0][wid * 512];
        u16* a1d = &Alds[1][wid * 512];
        u16* b1d = &Blds[1][wid * 512];
        #pragma unroll
        for (int q = 0; q < 4; ++q) gload16(paq[q],      a0d + q * 4096);
        #pragma unroll
        for (int q = 0; q < 4; ++q) gload16(pbq[q],      b0d + q * 4096);
        #pragma unroll
        for (int q = 0; q < 4; ++q) gload16(paq[q] + 64, a1d + q * 4096);
        #pragma unroll
        for (int q = 0; q < 4; ++q) gload16(pbq[q] + 64, b1d + q * 4096);
    }
    asm volatile("s_waitcnt vmcnt(8)" ::: "memory");
    __builtin_amdgcn_sched_barrier(0);
    __builtin_amdgcn_s_barrier();

    f32x4 acc[8][4] = {};
    bf16x8 a0[4][2], b0[2][2], b1[2][2];

    #pragma unroll 1
    for (int t = 0; t < SC_NT; ++t) {
        const int  b        = t & 1;
        const bool do_stage = (t + 2) < SC_NT;
        const int  k2  = (t + 2) * 64;
        const int  ka2 = (k2 < 2048) ? k2 : k2 - 2048;  // [Ah|Al|Ah]
        const int  kb2 = (k2 < 1024) ? k2 : k2 - 1024;  // [Bh|Bh|Bl]
        u16* ald = &Alds[b][wid * 512];
        u16* bld = &Blds[b][wid * 512];

        // ---- phase 0: read A-quad0 (8) + B-pair0 (4); MFMA (Ma, N0)
        #pragma unroll
        for (int i = 0; i < 4; ++i) {
            a0[i][0] = *(const bf16x8*)&Alds[b][ar + i * 1024 + c0];
            a0[i][1] = *(const bf16x8*)&Alds[b][ar + i * 1024 + c1];
        }
        #pragma unroll
        for (int g = 0; g < 2; ++g) {
            b0[g][0] = *(const bf16x8*)&Blds[b][br + g * 1024 + c0];
            b0[g][1] = *(const bf16x8*)&Blds[b][br + g * 1024 + c1];
        }
        __builtin_amdgcn_s_barrier();
        asm volatile("s_waitcnt lgkmcnt(0)" ::: "memory");
        __builtin_amdgcn_sched_barrier(0);
        __builtin_amdgcn_s_setprio(1);
        #pragma unroll
        for (int i = 0; i < 4; ++i)
            #pragma unroll
            for (int g = 0; g < 2; ++g)
                #pragma unroll
                for (int ks = 0; ks < 2; ++ks)
                    acc[i][g] = __builtin_amdgcn_mfma_f32_16x16x32_bf16(a0[i][ks], b0[g][ks], acc[i][g], 0, 0, 0);
        __builtin_amdgcn_s_setprio(0);
        __builtin_amdgcn_s_barrier();

        // ---- phase 1: read B-pair1 (4); stage A-Q0,A-Q2(t+2); MFMA (Ma, N1)
        #pragma unroll
        for (int g = 0; g < 2; ++g) {
            b1[g][0] = *(const bf16x8*)&Blds[b][br + 2048 + g * 1024 + c0];
            b1[g][1] = *(const bf16x8*)&Blds[b][br + 2048 + g * 1024 + c1];
        }
        if (do_stage) {
            gload16(paq[0] + ka2, ald);
            gload16(paq[2] + ka2, ald + 2 * 4096);
        }
        __builtin_amdgcn_s_barrier();
        asm volatile("s_waitcnt lgkmcnt(0)" ::: "memory");
        __builtin_amdgcn_sched_barrier(0);
        __builtin_amdgcn_s_setprio(1);
        #pragma unroll
        for (int i = 0; i < 4; ++i)
            #pragma unroll
            for (int g = 0; g < 2; ++g)
                #pragma unroll
                for (int ks = 0; ks < 2; ++ks)
                    acc[i][2 + g] = __builtin_amdgcn_mfma_f32_16x16x32_bf16(a0[i][ks], b1[g][ks], acc[i][2 + g], 0, 0, 0);
        __builtin_amdgcn_s_setprio(0);
        __builtin_amdgcn_s_barrier();

        // ---- phase 2: read A-quad1 (8); stage B-Q0..Q3(t+2); MFMA (Mb, N1)
        #pragma unroll
        for (int i = 0; i < 4; ++i) {
            a0[i][0] = *(const bf16x8*)&Alds[b][ar + 4096 + i * 1024 + c0];
            a0[i][1] = *(const bf16x8*)&Alds[b][ar + 4096 + i * 1024 + c1];
        }
        if (do_stage) {
            gload16(pbq[0] + kb2, bld);
            gload16(pbq[1] + kb2, bld + 4096);
            gload16(pbq[2] + kb2, bld + 2 * 4096);
            gload16(pbq[3] + kb2, bld + 3 * 4096);
        }
        __builtin_amdgcn_s_barrier();
        asm volatile("s_waitcnt lgkmcnt(0)" ::: "memory");
        __builtin_amdgcn_sched_barrier(0);
        __builtin_amdgcn_s_setprio(1);
        #pragma unroll
        for (int i = 0; i < 4; ++i)
            #pragma unroll
            for (int g = 0; g < 2; ++g)
                #pragma unroll
                for (int ks = 0; ks < 2; ++ks)
                    acc[4 + i][2 + g] = __builtin_amdgcn_mfma_f32_16x16x32_bf16(a0[i][ks], b1[g][ks], acc[4 + i][2 + g], 0, 0, 0);
        __builtin_amdgcn_s_setprio(0);
        __builtin_amdgcn_s_barrier();

        // ---- phase 3: stage A-Q1,A-Q3(t+2); MFMA (Mb, N0); vmcnt; barrier
        if (do_stage) {
            gload16(paq[1] + ka2, ald + 4096);
            gload16(paq[3] + ka2, ald + 3 * 4096);
        }
        __builtin_amdgcn_s_barrier();
        __builtin_amdgcn_s_setprio(1);
        #pragma unroll
        for (int i = 0; i < 4; ++i)
            #pragma unroll
            for (int g = 0; g < 2; ++g)
                #pragma unroll
                for (int ks = 0; ks < 2; ++ks)
                    acc[4 + i][g] = __builtin_amdgcn_mfma_f32_16x16x32_bf16(a0[i][ks], b0[g][ks], acc[4 + i][g], 0, 0, 0);
        __builtin_amdgcn_s_setprio(0);
        if (t < SC_NT - 2) { asm volatile("s_waitcnt vmcnt(8)" ::: "memory"); }
        else               { asm volatile("s_waitcnt vmcnt(0)" ::: "memory"); }
        __builtin_amdgcn_sched_barrier(0);
        __builtin_amdgcn_s_barrier();
    }

    // epilogue: C/D layout col=lane&15, row=(lane>>4)*4+reg
    const int crow0 = m0 + wm * 128 + half * 4;
    const int ccol0 = n0 + wn * 64 + l16;
    if constexpr (EPI == 0) {
        #pragma unroll
        for (int mf = 0; mf < 8; ++mf)
            #pragma unroll
            for (int nf = 0; nf < 4; ++nf)
                #pragma unroll
                for (int r = 0; r < 4; ++r)
                    C[(size_t)(crow0 + mf * 16 + r) * SEQ + ccol0 + nf * 16] = acc[mf][nf][r];
    } else {
        const int reg = n0 >> 10;   // 0=q, 1=k, 2=v (256-tile lies in one region)
        #pragma unroll
        for (int mf = 0; mf < 8; ++mf)
            #pragma unroll
            for (int nf = 0; nf < 4; ++nf)
                #pragma unroll
                for (int r = 0; r < 4; ++r) {
                    const int row = crow0 + mf * 16 + r;
                    const int c   = (ccol0 + nf * 16) & 1023;
                    const float val = acc[mf][nf][r];
                    const u16 hi = f2bf(val);
                    if (reg == 0) {
                        O0[(size_t)row * 2048 + c]        = hi;
                        O0[(size_t)row * 2048 + c + 1024] = f2bf(val - bf2f(hi));
                    } else if (reg == 1) {
                        O1[(size_t)row * 2048 + c]        = hi;
                        O1[(size_t)row * 2048 + c + 1024] = f2bf(val - bf2f(hi));
                    } else {
                        OT[(size_t)c * SEQ + row] = hi;
                    }
                }
    }
}

// ---------------------------------------------------------------------------
// Kernel 4: row softmax over fp32 [SEQ, SEQ]; writes bf16 P packed in-place
// ---------------------------------------------------------------------------
__global__ __launch_bounds__(256) void softmax_rows(float* __restrict__ S)
{
    const int row  = blockIdx.x;
    const int t    = threadIdx.x;
    const int lane = t & 63, wave = t >> 6;
    float* rp = S + (size_t)row * SEQ;

    float v[16];
    #pragma unroll
    for (int i = 0; i < 4; ++i) {
        float4 f = *(const float4*)(rp + i * 1024 + t * 4);
        v[i*4+0] = f.x; v[i*4+1] = f.y; v[i*4+2] = f.z; v[i*4+3] = f.w;
    }

    float m = v[0];
    #pragma unroll
    for (int i = 1; i < 16; ++i) m = fmaxf(m, v[i]);
    #pragma unroll
    for (int off = 32; off > 0; off >>= 1) m = fmaxf(m, __shfl_down(m, off));
    __shared__ float red[4];
    if (lane == 0) red[wave] = m;
    __syncthreads();
    m = fmaxf(fmaxf(red[0], red[1]), fmaxf(red[2], red[3]));
    __syncthreads();

    float s = 0.0f;
    #pragma unroll
    for (int i = 0; i < 16; ++i) { v[i] = __expf(v[i] - m); s += v[i]; }
    #pragma unroll
    for (int off = 32; off > 0; off >>= 1) s += __shfl_down(s, off);
    if (lane == 0) red[wave] = s;
    __syncthreads();
    s = red[0] + red[1] + red[2] + red[3];
    float inv = 1.0f / s;

    u16* op = (u16*)rp;
    #pragma unroll
    for (int i = 0; i < 4; ++i) {
        ushort4 o;
        o.x = f2bf(v[i*4+0] * inv);
        o.y = f2bf(v[i*4+1] * inv);
        o.z = f2bf(v[i*4+2] * inv);
        o.w = f2bf(v[i*4+3] * inv);
        *(ushort4*)(op + i * 1024 + t * 4) = o;
    }
}

// ---------------------------------------------------------------------------
// Kernel 5: PV GEMM, split-K=2 (512 blocks -> 2/CU).
// ---------------------------------------------------------------------------
__global__ __launch_bounds__(256, 3) void gemm_pv_partial(
    const u16* __restrict__ A, const u16* __restrict__ B,
    float* __restrict__ P0, float* __restrict__ P1)
{
    __shared__ __align__(16) u16 As[128 * 32];
    __shared__ __align__(16) u16 Bs[128 * 32];

    const int tid  = threadIdx.x;
    const int lane = tid & 63;
    const int wave = tid >> 6;
    const int m0   = blockIdx.y * 128;
    const int n0   = blockIdx.x * 128;
    const int wr   = (wave >> 1) * 64;
    const int wc   = (wave & 1) * 64;
    const int half = lane >> 4;
    const int l16  = lane & 15;

    float* C = blockIdx.z ? P1 : P0;
    const int kbase = blockIdx.z * 2048;

    f32x4 acc[4][4] = {};
    const int arow = tid >> 2;
    const int acol = (tid & 3) * 8;
    const int wb   = wave * 512;

    for (int k0 = kbase; k0 < kbase + 2048; k0 += 32) {
        __syncthreads();
        gload16(A + (size_t)(m0 + arow)      * 8192 + k0 + acol, &As[wb]);
        gload16(A + (size_t)(m0 + 64 + arow) * 8192 + k0 + acol, &As[2048 + wb]);
        gload16(B + (size_t)(n0 + arow)      * 4096 + k0 + acol, &Bs[wb]);
        gload16(B + (size_t)(n0 + 64 + arow) * 4096 + k0 + acol, &Bs[2048 + wb]);
        __syncthreads();

        bf16x8 af[4], bfr[4];
        #pragma unroll
        for (int i = 0; i < 4; ++i)
            af[i] = *(const bf16x8*)&As[(wr + i*16 + l16) * 32 + half * 8];
        #pragma unroll
        for (int j = 0; j < 4; ++j)
            bfr[j] = *(const bf16x8*)&Bs[(wc + j*16 + l16) * 32 + half * 8];
        #pragma unroll
        for (int i = 0; i < 4; ++i)
            #pragma unroll
            for (int j = 0; j < 4; ++j)
                acc[i][j] = __builtin_amdgcn_mfma_f32_16x16x32_bf16(af[i], bfr[j], acc[i][j], 0, 0, 0);
    }

    #pragma unroll
    for (int i = 0; i < 4; ++i)
        #pragma unroll
        for (int j = 0; j < 4; ++j)
            #pragma unroll
            for (int r = 0; r < 4; ++r) {
                int row = m0 + wr + i * 16 + half * 4 + r;
                int col = n0 + wc + j * 16 + l16;
                C[(size_t)row * DIM + col] = acc[i][j][r];
            }
}

// ---------------------------------------------------------------------------
// Kernel 6: out = silu(P0 + P1)
// ---------------------------------------------------------------------------
__global__ __launch_bounds__(256) void combine_silu(
    const float* __restrict__ P0, const float* __restrict__ P1,
    float* __restrict__ out)
{
    const int i = (blockIdx.x * 256 + threadIdx.x) * 4;
    float4 a = *(const float4*)(P0 + i);
    float4 b = *(const float4*)(P1 + i);
    float4 o;
    float v;
    v = a.x + b.x; o.x = v / (1.0f + __expf(-v));
    v = a.y + b.y; o.y = v / (1.0f + __expf(-v));
    v = a.z + b.z; o.z = v / (1.0f + __expf(-v));
    v = a.w + b.w; o.w = v / (1.0f + __expf(-v));
    *(float4*)(out + i) = o;
}

// ---------------------------------------------------------------------------
extern "C" void kernel_launch(void* const* d_in, const int* in_sizes, int n_in,
                              void* d_out, int out_size, void* d_ws, size_t ws_size,
                              hipStream_t stream)
{
    const int*   x   = (const int*)d_in[0];
    const float* emb = (const float*)d_in[1];
    const float* nw  = (const float*)d_in[2];
    const float* Wq  = (const float*)d_in[3];
    const float* Wk  = (const float*)d_in[4];
    const float* Wv  = (const float*)d_in[5];
    float* out = (float*)d_out;

    // ws layout (104 MB total, proven):
    //   [  0,  8) vT   bf16 [DIM,SEQ]             (QKV -> PV)
    //   [  8, 24) qhl  bf16 [SEQ,2048]=[qh|ql]    (QKV -> Sc)
    //   [ 24, 40) khl  bf16 [SEQ,2048]=[kh|kl]    (QKV -> Sc)
    //   [ 40,104) Sc   fp32 [SEQ,SEQ]
    //   hhl[40,56) Whl[56,68) overlap Sc head; dead before Sc GEMM writes.
    //   P0[8,24) P1[24,40) overlap q/k; q/k dead before PV writes.
    char* ws = (char*)d_ws;
    u16*   vT  = (u16*)(ws);
    u16*   qhl = (u16*)(ws + ( 8u << 20));
    u16*   khl = (u16*)(ws + (24u << 20));
    float* Sc  = (float*)(ws + (40u << 20));
    u16*   hhl = (u16*)(ws + (40u << 20));   // [4096,2048] hi|lo
    u16*   Whl = (u16*)(ws + (56u << 20));   // [3072,2048] hi|lo
    float* P0  = (float*)(ws + ( 8u << 20));
    float* P1  = (float*)(ws + (24u << 20));

    embed_rmsnorm_split<<<SEQ, 256, 0, stream>>>(x, emb, nw, hhl);
    split_w<<<dim3(DIM * DIM / 1024, 3), 256, 0, stream>>>(Wq, Wk, Wv, Whl);

    // fused QKV: [4096,3072] = (hh+hl) x (Wh+Wl)^T via virtual K'=3072
    gemm3072_8ph<1><<<dim3(3072 / 256, SEQ / 256), 512, 0, stream>>>(
        hhl, Whl, nullptr, qhl, khl, vT);

    // Sc = q.k^T via virtual K'=3072
    gemm3072_8ph<0><<<dim3(SEQ / 256, SEQ / 256), 512, 0, stream>>>(
        qhl, khl, Sc, nullptr, nullptr, nullptr);

    softmax_rows<<<SEQ, 256, 0, stream>>>(Sc);

    gemm_pv_partial<<<dim3(DIM / 128, SEQ / 128, 2), 256, 0, stream>>>(
        (const u16*)Sc, vT, P0, P1);

    combine_silu<<<SEQ * DIM / 1024, 256, 0, stream>>>(P0, P1, out);
}

// Round 5
// 452.571 us; speedup vs baseline: 1.0260x; 1.0260x over previous
//
#include <hip/hip_runtime.h>
#include <stdint.h>

#define SEQ 4096
#define DIM 1024

typedef __bf16 bf16x8 __attribute__((ext_vector_type(8)));
typedef float f32x4 __attribute__((ext_vector_type(4)));
typedef unsigned short u16;

__device__ __forceinline__ u16 f2bf(float f) {
    unsigned u = __float_as_uint(f);
    u += 0x7fffu + ((u >> 16) & 1u);     // RNE
    return (u16)(u >> 16);
}
__device__ __forceinline__ float bf2f(u16 h) {
    return __uint_as_float(((unsigned)h) << 16);
}

// global(16B) -> LDS direct copy; LDS dest is wave-uniform base + lane*16.
__device__ __forceinline__ void gload16(const u16* g, u16* l) {
    __builtin_amdgcn_global_load_lds(
        (const __attribute__((address_space(1))) void*)g,
        (__attribute__((address_space(3))) void*)l, 16, 0, 0);
}

// ---------------------------------------------------------------------------
// Kernel 1: h = rmsnorm(emb[x]) * norm_w, written as COMBINED hi|lo bf16
// hhl[4096][2048]: cols 0-1023 = hi, 1024-2047 = lo.
// ---------------------------------------------------------------------------
__global__ __launch_bounds__(256) void embed_rmsnorm_split(
    const int* __restrict__ x, const float* __restrict__ emb,
    const float* __restrict__ nw, u16* __restrict__ hhl)
{
    const int row  = blockIdx.x;
    const int t    = threadIdx.x;
    const int lane = t & 63, wave = t >> 6;

    bool i64 = true;
    #pragma unroll
    for (int i = 1; i < 128; i += 2) i64 = i64 && (x[i] == 0);
    const int id = i64 ? x[2 * row] : x[row];

    float4 e = *(const float4*)(emb + (size_t)id * DIM + t * 4);
    float ss = e.x*e.x + e.y*e.y + e.z*e.z + e.w*e.w;
    #pragma unroll
    for (int off = 32; off > 0; off >>= 1) ss += __shfl_down(ss, off);

    __shared__ float red[4];
    if (lane == 0) red[wave] = ss;
    __syncthreads();
    float sum = red[0] + red[1] + red[2] + red[3];
    float scale = rsqrtf(sum * (1.0f / DIM) + 1.1920929e-7f);  // fp32 eps

    float4 n = *(const float4*)(nw + t * 4);
    float o0 = e.x * scale * n.x;
    float o1 = e.y * scale * n.y;
    float o2 = e.z * scale * n.z;
    float o3 = e.w * scale * n.w;
    ushort4 oh, ol;
    u16 b;
    b = f2bf(o0); oh.x = b; ol.x = f2bf(o0 - bf2f(b));
    b = f2bf(o1); oh.y = b; ol.y = f2bf(o1 - bf2f(b));
    b = f2bf(o2); oh.z = b; ol.z = f2bf(o2 - bf2f(b));
    b = f2bf(o3); oh.w = b; ol.w = f2bf(o3 - bf2f(b));
    *(ushort4*)(hhl + (size_t)row * 2048 + t * 4)        = oh;
    *(ushort4*)(hhl + (size_t)row * 2048 + t * 4 + 1024) = ol;
}

// ---------------------------------------------------------------------------
// Kernel 1b: split Wq/Wk/Wv fp32 -> COMBINED hi|lo bf16 Whl[3072][2048]
// ---------------------------------------------------------------------------
__global__ __launch_bounds__(256) void split_w(
    const float* __restrict__ W0, const float* __restrict__ W1,
    const float* __restrict__ W2, u16* __restrict__ Whl)
{
    const float* W = (blockIdx.y == 0) ? W0 : (blockIdx.y == 1) ? W1 : W2;
    const int i   = (blockIdx.x * 256 + threadIdx.x) * 4;
    const int row = i >> 10;
    const int col = i & 1023;
    float4 w = *(const float4*)(W + i);
    ushort4 h, l;
    u16 b;
    b = f2bf(w.x); h.x = b; l.x = f2bf(w.x - bf2f(b));
    b = f2bf(w.y); h.y = b; l.y = f2bf(w.y - bf2f(b));
    b = f2bf(w.z); h.z = b; l.z = f2bf(w.z - bf2f(b));
    b = f2bf(w.w); h.w = b; l.w = f2bf(w.w - bf2f(b));
    u16* d = Whl + (size_t)(blockIdx.y * 1024 + row) * 2048 + col;
    *(ushort4*)(d)        = h;
    *(ushort4*)(d + 1024) = l;
}

// ---------------------------------------------------------------------------
// Kernel 2: TRUE-K split-precision 256x256 8-phase GEMM, BK=32, K=1024.
// All four operands (Ah/Al/Bh/Bl) staged in LDS simultaneously:
//   acc += Ah.Bh + Ah.Bl + Al.Bh per 32-K tile (R1-proven order).
// vs the virtual-K'=3072 version: same MFMA count, 32 tiles not 48
// (-33% phase overhead) and no segment re-reads (-60% staged bytes).
// LDS = 4 arrays x 2 buf x 256x32 bf16 = 128 KiB. 8 waves (2Mx4N).
//
// Bank math (rows = 32 u16 = 16 banks): bank = 16*(row&1) + dword-col.
// Read col = 8*(half ^ ((l16>>1)&3)) u16  -> 8 dwords/bank, balanced (free).
// Source permute (both-sides involution): col8' = (t&3) ^ ((t>>3)&3).
//
// Phase plan (per tile t, buffer b=t&1, staging t+2 into b):
//  p0: read Ah/Al mf0-3 + Bh/Bl nf0-1 (12);           MFMA acc[0-3][0-1] (24)
//  p1: read Bh/Bl nf2-3 (4);                          MFMA acc[0-3][2-3] (24)
//  p2: read Ah/Al mf4-7 (8); stage Bh,Bl u0,u1 (4);   MFMA acc[4-7][2-3] (24)
//      (B fully read by p1-end barrier -> stage safe)
//  p3: stage Ah,Al u0,u1 (4);                         MFMA acc[4-7][0-1] (24)
//      (A fully read by p2-end barrier); vmcnt(8); barrier
// EPI=0: C fp32 [SEQ,SEQ].  EPI=1: QKV split-write qhl/khl + vT transposed.
// ---------------------------------------------------------------------------
#define NT32 32
template<int EPI>
__global__ __launch_bounds__(512, 2) void gemm_bk32(
    const u16* __restrict__ A, const u16* __restrict__ B,
    float* __restrict__ C,
    u16* __restrict__ O0, u16* __restrict__ O1, u16* __restrict__ OT)
{
    __shared__ __align__(16) u16 AhL[2][8192];
    __shared__ __align__(16) u16 AlL[2][8192];
    __shared__ __align__(16) u16 BhL[2][8192];
    __shared__ __align__(16) u16 BlL[2][8192];

    const int tid  = threadIdx.x;
    const int lane = tid & 63;
    const int wid  = tid >> 6;
    const int wm   = wid >> 2;      // 0..1
    const int wn   = wid & 3;       // 0..3
    const int l16  = lane & 15;
    const int half = lane >> 4;     // 0..3

    // XCD-aware bijective swizzle (nwg = 256 or 192, both % 8 == 0)
    const int nx  = gridDim.x;
    const int nwg = nx * gridDim.y;
    const int wg  = blockIdx.y * nx + blockIdx.x;
    const int swz = (wg & 7) * (nwg >> 3) + (wg >> 3);
    const int m0  = (swz / nx) * 256;
    const int n0  = (swz % nx) * 256;

    // staging: thread t -> row t>>2 (0..127 within 128-row unit),
    // source col pre-permuted so linear LDS == swizzled layout
    const int srow = tid >> 2;
    const int scol = ((tid & 3) ^ ((tid >> 3) & 3)) * 8;
    const int ldst = tid * 8;                      // u16 offset within unit
    const u16* pAh[2]; const u16* pAl[2]; const u16* pBh[2]; const u16* pBl[2];
    #pragma unroll
    for (int u = 0; u < 2; ++u) {
        const size_t ao = (size_t)(m0 + u * 128 + srow) * 2048 + scol;
        const size_t bo = (size_t)(n0 + u * 128 + srow) * 2048 + scol;
        pAh[u] = A + ao;  pAl[u] = A + ao + 1024;
        pBh[u] = B + bo;  pBl[u] = B + bo + 1024;
    }

    // -------- prologue: stage tile0 -> buf0 (k=0), tile1 -> buf1 (k=32)
    #pragma unroll
    for (int kk = 0; kk < 2; ++kk)
        #pragma unroll
        for (int u = 0; u < 2; ++u) {
            gload16(pAh[u] + kk * 32, &AhL[kk][u * 4096 + ldst]);
            gload16(pAl[u] + kk * 32, &AlL[kk][u * 4096 + ldst]);
            gload16(pBh[u] + kk * 32, &BhL[kk][u * 4096 + ldst]);
            gload16(pBl[u] + kk * 32, &BlL[kk][u * 4096 + ldst]);
        }
    asm volatile("s_waitcnt vmcnt(8)" ::: "memory");
    __builtin_amdgcn_sched_barrier(0);
    __builtin_amdgcn_s_barrier();

    f32x4 acc[8][4] = {};
    // read addressing: bank-balanced col (derivation in header comment)
    const int rc = 8 * (half ^ ((l16 >> 1) & 3));
    const int ab = (wm * 128 + l16) * 32 + rc;   // + mf*512
    const int bb = (wn * 64  + l16) * 32 + rc;   // + nf*512

    bf16x8 ah[4], al[4], bh[4], bl[4];

    #pragma unroll 1
    for (int t = 0; t < NT32; ++t) {
        const int  b  = t & 1;
        const bool ds = (t + 2) < NT32;
        const int  k2 = (t + 2) * 32;

        // ---- phase 0
        #pragma unroll
        for (int i = 0; i < 4; ++i) {
            ah[i] = *(const bf16x8*)&AhL[b][ab + i * 512];
            al[i] = *(const bf16x8*)&AlL[b][ab + i * 512];
        }
        #pragma unroll
        for (int g = 0; g < 2; ++g) {
            bh[g] = *(const bf16x8*)&BhL[b][bb + g * 512];
            bl[g] = *(const bf16x8*)&BlL[b][bb + g * 512];
        }
        __builtin_amdgcn_s_barrier();
        asm volatile("s_waitcnt lgkmcnt(0)" ::: "memory");
        __builtin_amdgcn_sched_barrier(0);
        __builtin_amdgcn_s_setprio(1);
        #pragma unroll
        for (int i = 0; i < 4; ++i)
            #pragma unroll
            for (int g = 0; g < 2; ++g) {
                acc[i][g] = __builtin_amdgcn_mfma_f32_16x16x32_bf16(ah[i], bh[g], acc[i][g], 0, 0, 0);
                acc[i][g] = __builtin_amdgcn_mfma_f32_16x16x32_bf16(ah[i], bl[g], acc[i][g], 0, 0, 0);
                acc[i][g] = __builtin_amdgcn_mfma_f32_16x16x32_bf16(al[i], bh[g], acc[i][g], 0, 0, 0);
            }
        __builtin_amdgcn_s_setprio(0);
        __builtin_amdgcn_s_barrier();

        // ---- phase 1
        #pragma unroll
        for (int g = 0; g < 2; ++g) {
            bh[2 + g] = *(const bf16x8*)&BhL[b][bb + (2 + g) * 512];
            bl[2 + g] = *(const bf16x8*)&BlL[b][bb + (2 + g) * 512];
        }
        __builtin_amdgcn_s_barrier();
        asm volatile("s_waitcnt lgkmcnt(0)" ::: "memory");
        __builtin_amdgcn_sched_barrier(0);
        __builtin_amdgcn_s_setprio(1);
        #pragma unroll
        for (int i = 0; i < 4; ++i)
            #pragma unroll
            for (int g = 0; g < 2; ++g) {
                acc[i][2 + g] = __builtin_amdgcn_mfma_f32_16x16x32_bf16(ah[i], bh[2 + g], acc[i][2 + g], 0, 0, 0);
                acc[i][2 + g] = __builtin_amdgcn_mfma_f32_16x16x32_bf16(ah[i], bl[2 + g], acc[i][2 + g], 0, 0, 0);
                acc[i][2 + g] = __builtin_amdgcn_mfma_f32_16x16x32_bf16(al[i], bh[2 + g], acc[i][2 + g], 0, 0, 0);
            }
        __builtin_amdgcn_s_setprio(0);
        __builtin_amdgcn_s_barrier();

        // ---- phase 2 (B fully read after p1-end barrier -> stage B here)
        #pragma unroll
        for (int i = 0; i < 4; ++i) {
            ah[i] = *(const bf16x8*)&AhL[b][ab + 2048 + i * 512];
            al[i] = *(const bf16x8*)&AlL[b][ab + 2048 + i * 512];
        }
        if (ds) {
            gload16(pBh[0] + k2, &BhL[b][ldst]);
            gload16(pBh[1] + k2, &BhL[b][4096 + ldst]);
            gload16(pBl[0] + k2, &BlL[b][ldst]);
            gload16(pBl[1] + k2, &BlL[b][4096 + ldst]);
        }
        __builtin_amdgcn_s_barrier();
        asm volatile("s_waitcnt lgkmcnt(0)" ::: "memory");
        __builtin_amdgcn_sched_barrier(0);
        __builtin_amdgcn_s_setprio(1);
        #pragma unroll
        for (int i = 0; i < 4; ++i)
            #pragma unroll
            for (int g = 0; g < 2; ++g) {
                acc[4 + i][2 + g] = __builtin_amdgcn_mfma_f32_16x16x32_bf16(ah[i], bh[2 + g], acc[4 + i][2 + g], 0, 0, 0);
                acc[4 + i][2 + g] = __builtin_amdgcn_mfma_f32_16x16x32_bf16(ah[i], bl[2 + g], acc[4 + i][2 + g], 0, 0, 0);
                acc[4 + i][2 + g] = __builtin_amdgcn_mfma_f32_16x16x32_bf16(al[i], bh[2 + g], acc[4 + i][2 + g], 0, 0, 0);
            }
        __builtin_amdgcn_s_setprio(0);
        __builtin_amdgcn_s_barrier();

        // ---- phase 3 (A fully read after p2-end barrier -> stage A here)
        if (ds) {
            gload16(pAh[0] + k2, &AhL[b][ldst]);
            gload16(pAh[1] + k2, &AhL[b][4096 + ldst]);
            gload16(pAl[0] + k2, &AlL[b][ldst]);
            gload16(pAl[1] + k2, &AlL[b][4096 + ldst]);
        }
        __builtin_amdgcn_s_barrier();
        __builtin_amdgcn_s_setprio(1);
        #pragma unroll
        for (int i = 0; i < 4; ++i)
            #pragma unroll
            for (int g = 0; g < 2; ++g) {
                acc[4 + i][g] = __builtin_amdgcn_mfma_f32_16x16x32_bf16(ah[i], bh[g], acc[4 + i][g], 0, 0, 0);
                acc[4 + i][g] = __builtin_amdgcn_mfma_f32_16x16x32_bf16(ah[i], bl[g], acc[4 + i][g], 0, 0, 0);
                acc[4 + i][g] = __builtin_amdgcn_mfma_f32_16x16x32_bf16(al[i], bh[g], acc[4 + i][g], 0, 0, 0);
            }
        __builtin_amdgcn_s_setprio(0);
        if (t < NT32 - 2) { asm volatile("s_waitcnt vmcnt(8)" ::: "memory"); }
        else              { asm volatile("s_waitcnt vmcnt(0)" ::: "memory"); }
        __builtin_amdgcn_sched_barrier(0);
        __builtin_amdgcn_s_barrier();
    }

    // epilogue: C/D layout col=lane&15, row=(lane>>4)*4+reg
    const int crow0 = m0 + wm * 128 + half * 4;
    const int ccol0 = n0 + wn * 64 + l16;
    if constexpr (EPI == 0) {
        #pragma unroll
        for (int mf = 0; mf < 8; ++mf)
            #pragma unroll
            for (int nf = 0; nf < 4; ++nf)
                #pragma unroll
                for (int r = 0; r < 4; ++r)
                    C[(size_t)(crow0 + mf * 16 + r) * SEQ + ccol0 + nf * 16] = acc[mf][nf][r];
    } else {
        const int reg = n0 >> 10;   // 0=q, 1=k, 2=v (256-tile lies in one region)
        #pragma unroll
        for (int mf = 0; mf < 8; ++mf)
            #pragma unroll
            for (int nf = 0; nf < 4; ++nf)
                #pragma unroll
                for (int r = 0; r < 4; ++r) {
                    const int row = crow0 + mf * 16 + r;
                    const int c   = (ccol0 + nf * 16) & 1023;
                    const float val = acc[mf][nf][r];
                    const u16 hi = f2bf(val);
                    if (reg == 0) {
                        O0[(size_t)row * 2048 + c]        = hi;
                        O0[(size_t)row * 2048 + c + 1024] = f2bf(val - bf2f(hi));
                    } else if (reg == 1) {
                        O1[(size_t)row * 2048 + c]        = hi;
                        O1[(size_t)row * 2048 + c + 1024] = f2bf(val - bf2f(hi));
                    } else {
                        OT[(size_t)c * SEQ + row] = hi;
                    }
                }
    }
}

// ---------------------------------------------------------------------------
// Kernel 4: row softmax over fp32 [SEQ, SEQ]; writes bf16 P packed in-place
// ---------------------------------------------------------------------------
__global__ __launch_bounds__(256) void softmax_rows(float* __restrict__ S)
{
    const int row  = blockIdx.x;
    const int t    = threadIdx.x;
    const int lane = t & 63, wave = t >> 6;
    float* rp = S + (size_t)row * SEQ;

    float v[16];
    #pragma unroll
    for (int i = 0; i < 4; ++i) {
        float4 f = *(const float4*)(rp + i * 1024 + t * 4);
        v[i*4+0] = f.x; v[i*4+1] = f.y; v[i*4+2] = f.z; v[i*4+3] = f.w;
    }

    float m = v[0];
    #pragma unroll
    for (int i = 1; i < 16; ++i) m = fmaxf(m, v[i]);
    #pragma unroll
    for (int off = 32; off > 0; off >>= 1) m = fmaxf(m, __shfl_down(m, off));
    __shared__ float red[4];
    if (lane == 0) red[wave] = m;
    __syncthreads();
    m = fmaxf(fmaxf(red[0], red[1]), fmaxf(red[2], red[3]));
    __syncthreads();

    float s = 0.0f;
    #pragma unroll
    for (int i = 0; i < 16; ++i) { v[i] = __expf(v[i] - m); s += v[i]; }
    #pragma unroll
    for (int off = 32; off > 0; off >>= 1) s += __shfl_down(s, off);
    if (lane == 0) red[wave] = s;
    __syncthreads();
    s = red[0] + red[1] + red[2] + red[3];
    float inv = 1.0f / s;

    u16* op = (u16*)rp;
    #pragma unroll
    for (int i = 0; i < 4; ++i) {
        ushort4 o;
        o.x = f2bf(v[i*4+0] * inv);
        o.y = f2bf(v[i*4+1] * inv);
        o.z = f2bf(v[i*4+2] * inv);
        o.w = f2bf(v[i*4+3] * inv);
        *(ushort4*)(op + i * 1024 + t * 4) = o;
    }
}

// ---------------------------------------------------------------------------
// Kernel 5: PV GEMM, split-K=2 (512 blocks -> 2/CU).
// ---------------------------------------------------------------------------
__global__ __launch_bounds__(256, 3) void gemm_pv_partial(
    const u16* __restrict__ A, const u16* __restrict__ B,
    float* __restrict__ P0, float* __restrict__ P1)
{
    __shared__ __align__(16) u16 As[128 * 32];
    __shared__ __align__(16) u16 Bs[128 * 32];

    const int tid  = threadIdx.x;
    const int lane = tid & 63;
    const int wave = tid >> 6;
    const int m0   = blockIdx.y * 128;
    const int n0   = blockIdx.x * 128;
    const int wr   = (wave >> 1) * 64;
    const int wc   = (wave & 1) * 64;
    const int half = lane >> 4;
    const int l16  = lane & 15;

    float* C = blockIdx.z ? P1 : P0;
    const int kbase = blockIdx.z * 2048;

    f32x4 acc[4][4] = {};
    const int arow = tid >> 2;
    const int acol = (tid & 3) * 8;
    const int wb   = wave * 512;

    for (int k0 = kbase; k0 < kbase + 2048; k0 += 32) {
        __syncthreads();
        gload16(A + (size_t)(m0 + arow)      * 8192 + k0 + acol, &As[wb]);
        gload16(A + (size_t)(m0 + 64 + arow) * 8192 + k0 + acol, &As[2048 + wb]);
        gload16(B + (size_t)(n0 + arow)      * 4096 + k0 + acol, &Bs[wb]);
        gload16(B + (size_t)(n0 + 64 + arow) * 4096 + k0 + acol, &Bs[2048 + wb]);
        __syncthreads();

        bf16x8 af[4], bfr[4];
        #pragma unroll
        for (int i = 0; i < 4; ++i)
            af[i] = *(const bf16x8*)&As[(wr + i*16 + l16) * 32 + half * 8];
        #pragma unroll
        for (int j = 0; j < 4; ++j)
            bfr[j] = *(const bf16x8*)&Bs[(wc + j*16 + l16) * 32 + half * 8];
        #pragma unroll
        for (int i = 0; i < 4; ++i)
            #pragma unroll
            for (int j = 0; j < 4; ++j)
                acc[i][j] = __builtin_amdgcn_mfma_f32_16x16x32_bf16(af[i], bfr[j], acc[i][j], 0, 0, 0);
    }

    #pragma unroll
    for (int i = 0; i < 4; ++i)
        #pragma unroll
        for (int j = 0; j < 4; ++j)
            #pragma unroll
            for (int r = 0; r < 4; ++r) {
                int row = m0 + wr + i * 16 + half * 4 + r;
                int col = n0 + wc + j * 16 + l16;
                C[(size_t)row * DIM + col] = acc[i][j][r];
            }
}

// ---------------------------------------------------------------------------
// Kernel 6: out = silu(P0 + P1)
// ---------------------------------------------------------------------------
__global__ __launch_bounds__(256) void combine_silu(
    const float* __restrict__ P0, const float* __restrict__ P1,
    float* __restrict__ out)
{
    const int i = (blockIdx.x * 256 + threadIdx.x) * 4;
    float4 a = *(const float4*)(P0 + i);
    float4 b = *(const float4*)(P1 + i);
    float4 o;
    float v;
    v = a.x + b.x; o.x = v / (1.0f + __expf(-v));
    v = a.y + b.y; o.y = v / (1.0f + __expf(-v));
    v = a.z + b.z; o.z = v / (1.0f + __expf(-v));
    v = a.w + b.w; o.w = v / (1.0f + __expf(-v));
    *(float4*)(out + i) = o;
}

// ---------------------------------------------------------------------------
extern "C" void kernel_launch(void* const* d_in, const int* in_sizes, int n_in,
                              void* d_out, int out_size, void* d_ws, size_t ws_size,
                              hipStream_t stream)
{
    const int*   x   = (const int*)d_in[0];
    const float* emb = (const float*)d_in[1];
    const float* nw  = (const float*)d_in[2];
    const float* Wq  = (const float*)d_in[3];
    const float* Wk  = (const float*)d_in[4];
    const float* Wv  = (const float*)d_in[5];
    float* out = (float*)d_out;

    // ws layout (104 MB total, proven):
    //   [  0,  8) vT   bf16 [DIM,SEQ]             (QKV -> PV)
    //   [  8, 24) qhl  bf16 [SEQ,2048]=[qh|ql]    (QKV -> Sc)
    //   [ 24, 40) khl  bf16 [SEQ,2048]=[kh|kl]    (QKV -> Sc)
    //   [ 40,104) Sc   fp32 [SEQ,SEQ]
    //   hhl[40,56) Whl[56,68) overlap Sc head; dead before Sc GEMM writes.
    //   P0[8,24) P1[24,40) overlap q/k; q/k dead before PV writes.
    char* ws = (char*)d_ws;
    u16*   vT  = (u16*)(ws);
    u16*   qhl = (u16*)(ws + ( 8u << 20));
    u16*   khl = (u16*)(ws + (24u << 20));
    float* Sc  = (float*)(ws + (40u << 20));
    u16*   hhl = (u16*)(ws + (40u << 20));   // [4096,2048] hi|lo
    u16*   Whl = (u16*)(ws + (56u << 20));   // [3072,2048] hi|lo
    float* P0  = (float*)(ws + ( 8u << 20));
    float* P1  = (float*)(ws + (24u << 20));

    embed_rmsnorm_split<<<SEQ, 256, 0, stream>>>(x, emb, nw, hhl);
    split_w<<<dim3(DIM * DIM / 1024, 3), 256, 0, stream>>>(Wq, Wk, Wv, Whl);

    // fused QKV: [4096,3072] = (hh+hl) x (Wh+Wl)^T, true-K=1024 BK=32 8-phase
    gemm_bk32<1><<<dim3(3072 / 256, SEQ / 256), 512, 0, stream>>>(
        hhl, Whl, nullptr, qhl, khl, vT);

    // Sc = q.k^T, true-K=1024 BK=32 8-phase
    gemm_bk32<0><<<dim3(SEQ / 256, SEQ / 256), 512, 0, stream>>>(
        qhl, khl, Sc, nullptr, nullptr, nullptr);

    softmax_rows<<<SEQ, 256, 0, stream>>>(Sc);

    gemm_pv_partial<<<dim3(DIM / 128, SEQ / 128, 2), 256, 0, stream>>>(
        (const u16*)Sc, vT, P0, P1);

    combine_silu<<<SEQ * DIM / 1024, 256, 0, stream>>>(P0, P1, out);
}